// Round 11
// baseline (299.223 us; speedup 1.0000x reference)
//
#include <hip/hip_runtime.h>
#include <hip/hip_bf16.h>

#define N_NODES 100000
#define N_EDGES 1600000
#define N_GRAPHS 512
#define NB 256                 // coarse dst-buckets
#define NPB 391                // nodes per bucket (256*391 = 100096 >= 100000)
#define CHUNK 6250             // edges per binning block (256*6250 = 1.6M exact)
#define STAGE 7680             // LDS csr staging per bucket (mean 6250, sd ~79)
#define GGROUPS 1563           // 64-row groups in gemm
#define GGRID 512              // gemm blocks (512 x 512thr = 1024 half-blocks, all resident)

typedef __attribute__((ext_vector_type(8))) short short8;
typedef __attribute__((ext_vector_type(4))) float f32x4;
typedef __attribute__((ext_vector_type(2))) float f32x2;

// ---- bf16 helpers ----
__device__ __forceinline__ float b2f(ushort u) {
    union { unsigned int i; float f; } c; c.i = ((unsigned int)u) << 16; return c.f;
}
__device__ __forceinline__ float blo(unsigned int u) {
    union { unsigned int i; float f; } c; c.i = u << 16; return c.f;
}
__device__ __forceinline__ float bhi(unsigned int u) {
    union { unsigned int i; float f; } c; c.i = u & 0xffff0000u; return c.f;
}
__device__ __forceinline__ ushort f2b(float f) {  // round-to-nearest-even
    union { float f; unsigned int i; } c; c.f = f;
    unsigned int r = (c.i + 0x7fffu + ((c.i >> 16) & 1u)) >> 16;
    return (ushort)r;
}
__device__ __forceinline__ unsigned int fbits(float f) {
    union { float f; unsigned int i; } c; c.f = f; return c.i;
}
__device__ __forceinline__ int idx_at(const void* p, long i, int f) {
    return f ? (int)((const long long*)p)[i] : ((const int*)p)[i];
}
// decode 8 packed fp8 -> short8 of bf16.
// fp8->f32 exact; bf16 mantissa (7b) superset of e4m3 (3b): truncation exact
// -> hi16 of two f32 packed with ONE v_perm_b32 each.
__device__ __forceinline__ short8 dec8(const uchar* p) {
    uint2 q = *(const uint2*)p;
    f32x2 d0 = __builtin_amdgcn_cvt_pk_f32_fp8((int)q.x, false);
    f32x2 d1 = __builtin_amdgcn_cvt_pk_f32_fp8((int)q.x, true);
    f32x2 d2 = __builtin_amdgcn_cvt_pk_f32_fp8((int)q.y, false);
    f32x2 d3 = __builtin_amdgcn_cvt_pk_f32_fp8((int)q.y, true);
    union { short8 s; unsigned int u[4]; } r;
    r.u[0] = __builtin_amdgcn_perm(fbits(d0.y), fbits(d0.x), 0x07060302u);
    r.u[1] = __builtin_amdgcn_perm(fbits(d1.y), fbits(d1.x), 0x07060302u);
    r.u[2] = __builtin_amdgcn_perm(fbits(d2.y), fbits(d2.x), 0x07060302u);
    r.u[3] = __builtin_amdgcn_perm(fbits(d3.y), fbits(d3.x), 0x07060302u);
    return r.s;
}

// ---- 1. fused prep (flags detected locally per block; block 0 publishes
//      global flags incl. batch dtype — k_flags launch eliminated):
//      [0,NB) bucket-hist (TRANSPOSED store: blkcnt[bucket][block]) |
//      [NB,NB+2048) cvt x -> xf8 | [.., +257) cvt_w | last 256 blocks zero gsum
__global__ __launch_bounds__(256) void k_prep(const void* __restrict__ ei,
                                              const void* __restrict__ x,
                                              const void* __restrict__ batch,
                                              unsigned int* __restrict__ xf8,
                                              const void* W1l, const void* W1r,
                                              const void* W2l, const void* W2r,
                                              const void* b1,  const void* b2,
                                              ushort* __restrict__ wbf,
                                              int* __restrict__ blkcnt,
                                              float* __restrict__ gsum,
                                              int* __restrict__ flags) {
    int b = blockIdx.x, t = threadIdx.x;
    __shared__ int cf, ce, cb;
    int f0 = 0, f1 = 0;
    if (b < NB + 2048 + 257) {               // zero-gsum blocks skip detection
        if (t == 0) { cf = 0; ce = 0; cb = 0; }
        __syncthreads();
        unsigned int w = ((const unsigned int*)x)[t];
        unsigned int e = (w >> 7) & 0xffu;
        if (e >= 110u && e <= 130u) atomicAdd(&cf, 1);
        if (t < 128) {
            if (((const unsigned int*)ei)[2 * t + 1] != 0u) atomicAdd(&ce, 1);
            if (b == 0 && ((const int*)batch)[99001 + 2 * t] != 0) atomicAdd(&cb, 1);
        }
        __syncthreads();
        f0 = (cf >= 128) ? 1 : 0;
        f1 = (ce == 0) ? 1 : 0;
        if (b == 0 && t == 0) {
            flags[0] = f0;
            flags[1] = f1;
            flags[2] = (cb == 0) ? 1 : 0;
        }
    }
    if (b < NB) {
        __shared__ int h[NB];
        for (int j = t; j < NB; j += 256) h[j] = 0;
        __syncthreads();
        int lo = b * CHUNK, hi = lo + CHUNK;
        for (int e = lo + t; e < hi; e += 256) {
            int d = idx_at(ei, (long)N_EDGES + e, f1);
            atomicAdd(&h[d / NPB], 1);
        }
        __syncthreads();
        if (t < NB) blkcnt[t * NB + b] = h[t];   // transposed: [bucket][block]
    } else if (b < NB + 2048) {
        bool f32src = (f0 == 0);
        int vb = b - NB;
        const long nG = (long)N_NODES * 128 / 4;   // 3.2M groups of 4 feats
        for (long g = (long)vb * 256 + t; g < nG; g += 2048L * 256) {
            float v0, v1, v2, v3;
            if (f32src) {
                float4 vv = ((const float4*)x)[g];
                v0 = vv.x; v1 = vv.y; v2 = vv.z; v3 = vv.w;
            } else {
                uint2 q = ((const uint2*)x)[g];
                v0 = blo(q.x); v1 = bhi(q.x); v2 = blo(q.y); v3 = bhi(q.y);
            }
            int r = __builtin_amdgcn_cvt_pk_fp8_f32(v0, v1, 0, false);
            r = __builtin_amdgcn_cvt_pk_fp8_f32(v2, v3, r, true);
            xf8[g] = (unsigned int)r;
        }
    } else if (b < NB + 2048 + 257) {
        // weights+biases -> bf16: W1l@0 W1r@16384 W2l@32768 W2r@49152 b1@65536 b2@65664
        int idx = (b - NB - 2048) * 256 + t;
        if (idx >= 65792) return;
        const void* src; int off;
        if      (idx < 16384) { src = W1l; off = idx; }
        else if (idx < 32768) { src = W1r; off = idx - 16384; }
        else if (idx < 49152) { src = W2l; off = idx - 32768; }
        else if (idx < 65536) { src = W2r; off = idx - 49152; }
        else if (idx < 65664) { src = b1;  off = idx - 65536; }
        else                  { src = b2;  off = idx - 65664; }
        wbf[idx] = (f0 != 0) ? ((const ushort*)src)[off]
                             : f2b(((const float*)src)[off]);
    } else {
        int idx = (b - NB - 2048 - 257) * 256 + t;   // 256 blocks * 256 = 65536 exact
        gsum[idx] = 0.f;
    }
}

// ---- 2a. parallel per-bucket block-prefix: 256 blocks, block j = bucket j.
//      Coalesced load of blkcnt[j][0..255], LDS scan, write within-bucket
//      exclusive prefix to blkbase[j][blk] and bucket total to tot[j]. ----
__global__ __launch_bounds__(NB) void k_bscan_a(const int* __restrict__ blkcnt,
                                                int* __restrict__ blkbase,
                                                int* __restrict__ tot) {
    __shared__ int s[NB];
    int j = blockIdx.x, t = threadIdx.x;
    int v = blkcnt[j * NB + t];
    s[t] = v; __syncthreads();
    for (int off = 1; off < NB; off <<= 1) {
        int a = (t >= off) ? s[t - off] : 0;
        __syncthreads();
        s[t] += a;
        __syncthreads();
    }
    blkbase[j * NB + t] = s[t] - v;          // exclusive within bucket
    if (t == NB - 1) tot[j] = s[t];
}

// ---- 2b. tiny cross-bucket scan: bucketBase = exclusive prefix of tot ----
__global__ __launch_bounds__(NB) void k_bscan_b(const int* __restrict__ tot,
                                                int* __restrict__ bucketBase) {
    __shared__ int s[NB];
    int t = threadIdx.x;
    int v = tot[t];
    s[t] = v; __syncthreads();
    for (int off = 1; off < NB; off <<= 1) {
        int a = (t >= off) ? s[t - off] : 0;
        __syncthreads();
        s[t] += a;
        __syncthreads();
    }
    bucketBase[t] = s[t] - v;
    if (t == NB - 1) bucketBase[NB] = s[t];
}

// ---- 3. bin edges into buckets; packed entry = src | (loc<<20) ----
__global__ __launch_bounds__(256) void k_bin(const void* __restrict__ ei,
                                             const int* __restrict__ blkbase,
                                             const int* __restrict__ bucketBase,
                                             int* __restrict__ binned,
                                             const int* __restrict__ flags) {
    __shared__ int bb[NB];
    __shared__ int rank[NB];
    int t = threadIdx.x, blk = blockIdx.x;
    int f = flags[1];
    for (int j = t; j < NB; j += 256) {
        bb[j] = blkbase[j * NB + blk] + bucketBase[j];
        rank[j] = 0;
    }
    __syncthreads();
    int lo = blk * CHUNK, hi = lo + CHUNK;
    for (int e = lo + t; e < hi; e += 256) {
        int s = idx_at(ei, e, f);
        int d = idx_at(ei, (long)N_EDGES + e, f);
        int b = d / NPB;
        int loc = d - b * NPB;              // 0..390, fits in 9 bits
        int r = atomicAdd(&rank[b], 1);
        binned[bb[b] + r] = s | (loc << 20);
    }
}

// ---- 4. per-bucket CSR in LDS, coalesced flush ----
__global__ __launch_bounds__(256) void k_csr(const int* __restrict__ binned,
                                             const int* __restrict__ bucketBase,
                                             int* __restrict__ rowptr,
                                             int* __restrict__ csr) {
    __shared__ int cnt[400];
    __shared__ int sc[400];
    __shared__ int sh[256];
    __shared__ int stage[STAGE];  // 30 KB
    int t = threadIdx.x, b = blockIdx.x;
    int nodeLo = b * NPB;
    int nC = N_NODES - nodeLo; if (nC > NPB) nC = NPB;
    int eBase = bucketBase[b], eEnd = bucketBase[b + 1];

    for (int j = t; j < 400; j += 256) cnt[j] = 0;
    __syncthreads();
    for (int i = eBase + t; i < eEnd; i += 256)
        atomicAdd(&cnt[binned[i] >> 20], 1);
    __syncthreads();
    int base = t * 2;
    int v0 = (base < 400) ? cnt[base] : 0;
    int v1 = (base + 1 < 400) ? cnt[base + 1] : 0;
    int ssum = v0 + v1;
    sh[t] = ssum; __syncthreads();
    for (int off = 1; off < 256; off <<= 1) {
        int a = (t >= off) ? sh[t - off] : 0;
        __syncthreads();
        sh[t] += a;
        __syncthreads();
    }
    int pre = sh[t] - ssum;
    if (base < 400) sc[base] = pre;
    if (base + 1 < 400) sc[base + 1] = pre + v0;
    __syncthreads();
    for (int j = t; j < nC; j += 256) rowptr[nodeLo + j] = eBase + sc[j];
    if (b == NB - 1) {
        if (t == 0) rowptr[N_NODES] = eEnd;
        if (t < 64) csr[N_EDGES + t] = 0;   // pad (agg clamps anyway)
    }
    for (int j = t; j < 400; j += 256) cnt[j] = 0;  // reuse as rank
    __syncthreads();
    for (int i = eBase + t; i < eEnd; i += 256) {
        int p = binned[i];
        int loc = p >> 20;
        int pos = sc[loc] + atomicAdd(&cnt[loc], 1);
        int srcn = p & 0xFFFFF;
        if (pos < STAGE) stage[pos] = srcn;
        else csr[eBase + pos] = srcn;   // statistical never
    }
    __syncthreads();
    int eCnt = eEnd - eBase; if (eCnt > STAGE) eCnt = STAGE;
    for (int j = t; j < eCnt; j += 256) csr[eBase + j] = stage[j];
}

// ---- 5. mean aggregation over fp8 rows: 8 nodes per wave (8 lanes each).
//      r7 8-deep loop (r8's 16-deep was VGPR-confounded: +32 VGPR cancelled
//      the 2x in-flight); __launch_bounds__(256,6) pins 6 waves/SIMD
//      (VGPR cap 85 >= ~70 live set) for max gather concurrency. ----
__global__ __launch_bounds__(256, 6) void k_agg(const uint4* __restrict__ x8,
                                                const int* __restrict__ rowptr,
                                                const int* __restrict__ csr,
                                                uint4* __restrict__ mout) {
    int wv = blockIdx.x * 4 + (threadIdx.x >> 6);   // wave id; 8 nodes per wave
    int lane = threadIdx.x & 63;
    int li = lane & 7;                              // lane within node-octet
    int node = wv * 8 + (lane >> 3);                // 100000 % 8 == 0: no tail
    int beg = rowptr[node];
    int end = rowptr[node + 1];
    int deg = end - beg;
    f32x2 a2[8] = {};
    int full = deg & ~7;
    int j = 0;
    for (; j < full; j += 8) {                      // all 8 edges valid: no guards
        int vidx = csr[beg + j + li];
        uint4 p[8];
#pragma unroll
        for (int i = 0; i < 8; ++i) {
            int idx = __shfl(vidx, i | (lane & 56));  // stays within 8-lane group
            p[i] = x8[(long)idx * 8 + li];            // 16 fp8 feats per lane
        }
#pragma unroll
        for (int i = 0; i < 8; ++i) {
            a2[0] += __builtin_amdgcn_cvt_pk_f32_fp8((int)p[i].x, false);
            a2[1] += __builtin_amdgcn_cvt_pk_f32_fp8((int)p[i].x, true);
            a2[2] += __builtin_amdgcn_cvt_pk_f32_fp8((int)p[i].y, false);
            a2[3] += __builtin_amdgcn_cvt_pk_f32_fp8((int)p[i].y, true);
            a2[4] += __builtin_amdgcn_cvt_pk_f32_fp8((int)p[i].z, false);
            a2[5] += __builtin_amdgcn_cvt_pk_f32_fp8((int)p[i].z, true);
            a2[6] += __builtin_amdgcn_cvt_pk_f32_fp8((int)p[i].w, false);
            a2[7] += __builtin_amdgcn_cvt_pk_f32_fp8((int)p[i].w, true);
        }
    }
    if (j < deg) {                                  // <=7 remaining, group-uniform
        int pos = beg + j + li;
        if (pos > end - 1) pos = end - 1;           // deg>0 here, so valid
        int vidx = csr[pos];
#pragma unroll
        for (int i = 0; i < 8; ++i) {
            int idx = __shfl(vidx, i | (lane & 56));
            uint4 p = x8[(long)idx * 8 + li];       // dup loads hit L1
            bool ok = (j + i < deg);
            unsigned int q0 = ok ? p.x : 0u;        // fp8 0x00 == 0.0
            unsigned int q1 = ok ? p.y : 0u;
            unsigned int q2 = ok ? p.z : 0u;
            unsigned int q3 = ok ? p.w : 0u;
            a2[0] += __builtin_amdgcn_cvt_pk_f32_fp8((int)q0, false);
            a2[1] += __builtin_amdgcn_cvt_pk_f32_fp8((int)q0, true);
            a2[2] += __builtin_amdgcn_cvt_pk_f32_fp8((int)q1, false);
            a2[3] += __builtin_amdgcn_cvt_pk_f32_fp8((int)q1, true);
            a2[4] += __builtin_amdgcn_cvt_pk_f32_fp8((int)q2, false);
            a2[5] += __builtin_amdgcn_cvt_pk_f32_fp8((int)q2, true);
            a2[6] += __builtin_amdgcn_cvt_pk_f32_fp8((int)q3, false);
            a2[7] += __builtin_amdgcn_cvt_pk_f32_fp8((int)q3, true);
        }
    }
    float s = (deg > 0) ? 1.f / (float)deg : 0.f;
    uint4 o;
    int r;
    r = __builtin_amdgcn_cvt_pk_fp8_f32(a2[0].x * s, a2[0].y * s, 0, false);
    r = __builtin_amdgcn_cvt_pk_fp8_f32(a2[1].x * s, a2[1].y * s, r, true);  o.x = (unsigned int)r;
    r = __builtin_amdgcn_cvt_pk_fp8_f32(a2[2].x * s, a2[2].y * s, 0, false);
    r = __builtin_amdgcn_cvt_pk_fp8_f32(a2[3].x * s, a2[3].y * s, r, true);  o.y = (unsigned int)r;
    r = __builtin_amdgcn_cvt_pk_fp8_f32(a2[4].x * s, a2[4].y * s, 0, false);
    r = __builtin_amdgcn_cvt_pk_fp8_f32(a2[5].x * s, a2[5].y * s, r, true);  o.z = (unsigned int)r;
    r = __builtin_amdgcn_cvt_pk_fp8_f32(a2[6].x * s, a2[6].y * s, 0, false);
    r = __builtin_amdgcn_cvt_pk_fp8_f32(a2[7].x * s, a2[7].y * s, r, true);  o.w = (unsigned int)r;
    mout[(long)node * 8 + li] = o;
}

// ---- 6. persistent fused SAGE linear: out = relu([A0|A1] @ [Wl;Wr]^T + b) ----
// FROZEN r9 config: 512-thread blocks (two independent halves, one 64KB Ws),
// 16 waves/CU, VGPR<=128 (no spill), serialized tiles, balanced partition.
__global__ __launch_bounds__(512, 2) void k_gemm(const uchar* __restrict__ A0f8,
                                                 const uchar* __restrict__ A1f8,
                                                 const ushort* __restrict__ Wl,
                                                 const ushort* __restrict__ Wr,
                                                 const ushort* __restrict__ bias,
                                                 uchar* __restrict__ out8,
                                                 float* __restrict__ gsum,
                                                 const void* __restrict__ batch,
                                                 const int* __restrict__ flags,
                                                 int layer1) {
    __shared__ short Ws[4096 * 8];  // 64 KiB fragment-interleaved weights (shared by both halves)
    int t = threadIdx.x;
#pragma unroll
    for (int i = 0; i < 8; ++i) {
        int f = i * 512 + t;
        int ln = f & 63, kk = (f >> 6) & 7, tile = f >> 9;
        int o = tile * 16 + (ln & 15);
        int k0 = kk * 32 + ((ln >> 4) * 8);
        const ushort* wsrc = (k0 < 128) ? (Wl + o * 128 + k0)
                                        : (Wr + o * 128 + (k0 - 128));
        *(short8*)&Ws[f * 8] = *(const short8*)wsrc;
    }
    __syncthreads();

    int half = t >> 8;              // which 256-thread half-block
    int tt = t & 255;
    int wid = tt >> 6, lane = tt & 63;
    int kq = (lane >> 4) * 8;
    int bflag = layer1 ? 0 : flags[2];

    // hoist bias for this lane's output column across all 8 tiles (8 VGPR)
    float bo8[8];
#pragma unroll
    for (int tile = 0; tile < 8; ++tile)
        bo8[tile] = b2f(bias[tile * 16 + (lane & 15)]);

    int h = blockIdx.x * 2 + half;               // 0..1023
    int gbeg = (h * GGROUPS) >> 10;              // balanced contiguous partition
    int gend = ((h + 1) * GGROUPS) >> 10;

    for (int g = gbeg; g < gend; ++g) {
        long nbase = (long)g * 64 + (long)wid * 16;
        int arow = (int)nbase + (lane & 15);
        if (arow >= N_NODES) arow = N_NODES - 1;   // clamp (stores guarded)

        short8 afrag[8];
#pragma unroll
        for (int kk = 0; kk < 8; ++kk) {
            int k0 = kk * 32 + kq;
            afrag[kk] = (k0 < 128)
                ? dec8(A0f8 + (long)arow * 128 + k0)
                : dec8(A1f8 + (long)arow * 128 + (k0 - 128));
        }

        int bg[4]; int guni = 0; bool uniform = false;
        if (!layer1) {
            int bmin = 0x7fffffff, bmax = -0x7fffffff;
#pragma unroll
            for (int r = 0; r < 4; ++r) {
                long node = nbase + (lane >> 4) * 4 + r;
                if (node < N_NODES) {
                    int bb = idx_at(batch, node, bflag);
                    bg[r] = bb;
                    bmin = min(bmin, bb); bmax = max(bmax, bb);
                } else { bg[r] = 0; bmax = 0x7fffffff; }  // force slow path on tail
            }
            bmin = min(bmin, __shfl_xor(bmin, 16));
            bmin = min(bmin, __shfl_xor(bmin, 32));
            bmax = max(bmax, __shfl_xor(bmax, 16));
            bmax = max(bmax, __shfl_xor(bmax, 32));
            uniform = (bmin == bmax);
            guni = bmin;
        }

#pragma unroll 1
        for (int tile = 0; tile < 8; ++tile) {
            f32x4 acc = {0.f, 0.f, 0.f, 0.f};
#pragma unroll
            for (int kk = 0; kk < 8; ++kk) {
                short8 bfrag = *(short8*)&Ws[((tile * 8 + kk) * 64 + lane) * 8];
                acc = __builtin_amdgcn_mfma_f32_16x16x32_bf16(afrag[kk], bfrag, acc, 0, 0, 0);
            }
            int o = tile * 16 + (lane & 15);
            float bo = bo8[tile];
            if (layer1) {
#pragma unroll
                for (int r = 0; r < 4; ++r) {
                    long node = nbase + (lane >> 4) * 4 + r;
                    if (node < N_NODES) {
                        float v = acc[r] + bo;
                        v = v > 0.f ? v : 0.f;
                        int pp = __builtin_amdgcn_cvt_pk_fp8_f32(v, v, 0, false);
                        out8[node * 128 + o] = (uchar)pp;
                    }
                }
            } else if (uniform) {
                float s = 0.f;
#pragma unroll
                for (int r = 0; r < 4; ++r) {
                    float v = acc[r] + bo;
                    s += (v > 0.f ? v : 0.f);
                }
                s += __shfl_xor(s, 16);
                s += __shfl_xor(s, 32);
                if ((lane >> 4) == 0) atomicAdd(&gsum[guni * 128 + o], s);
            } else {
#pragma unroll
                for (int r = 0; r < 4; ++r) {
                    long node = nbase + (lane >> 4) * 4 + r;
                    if (node < N_NODES) {
                        float v = acc[r] + bo;
                        v = v > 0.f ? v : 0.f;
                        atomicAdd(&gsum[bg[r] * 128 + o], v);
                    }
                }
            }
        }
    }
}

// ---- 7. tiny classifier: mean = gsum/cnt ; logits = Wf@mean + bf ; log_softmax ----
__global__ __launch_bounds__(128) void k_cls(const float* __restrict__ gsum,
                                             const void* __restrict__ batch,
                                             const void* __restrict__ Wf,
                                             const void* __restrict__ bfv,
                                             void* __restrict__ outp,
                                             const int* __restrict__ flags) {
    int g = blockIdx.x, t = threadIdx.x;
    bool f32 = (flags[0] == 0);
    int b64 = flags[2];
    __shared__ int rng[2];
    __shared__ float gv[128];
    __shared__ float lg[10];
    if (t < 2) {
        int v = g + t, lo = 0, hi = N_NODES;
        while (lo < hi) {
            int mid = (lo + hi) >> 1;
            if (idx_at(batch, mid, b64) < v) lo = mid + 1; else hi = mid;
        }
        rng[t] = lo;
    }
    __syncthreads();
    int cnt = rng[1] - rng[0];
    float c = (cnt > 0) ? (float)cnt : 1.f;
    gv[t] = gsum[g * 128 + t] / c;
    __syncthreads();
    if (t < 10) {
        float s = f32 ? ((const float*)bfv)[t] : b2f(((const ushort*)bfv)[t]);
        for (int k = 0; k < 128; ++k) {
            float wv = f32 ? ((const float*)Wf)[t * 128 + k] : b2f(((const ushort*)Wf)[t * 128 + k]);
            s += gv[k] * wv;
        }
        lg[t] = s;
    }
    __syncthreads();
    if (t == 0) {
        float mx = lg[0];
        for (int i = 1; i < 10; ++i) mx = fmaxf(mx, lg[i]);
        float se = 0.f;
        for (int i = 0; i < 10; ++i) se += expf(lg[i] - mx);
        float lse = mx + logf(se);
        for (int i = 0; i < 10; ++i) {
            float v = lg[i] - lse;
            if (f32) ((float*)outp)[g * 10 + i] = v;
            else     ((ushort*)outp)[g * 10 + i] = f2b(v);
        }
    }
}

extern "C" void kernel_launch(void* const* d_in, const int* in_sizes, int n_in,
                              void* d_out, int out_size, void* d_ws, size_t ws_size,
                              hipStream_t stream) {
    const void* x     = d_in[0];
    const void* ei    = d_in[1];
    const void* batch = d_in[2];
    const void* W1l = d_in[3];
    const void* b1  = d_in[4];
    const void* W1r = d_in[5];
    const void* W2l = d_in[6];
    const void* b2  = d_in[7];
    const void* W2r = d_in[8];
    const void* Wf  = d_in[9];
    const void* bf_ = d_in[10];

    // workspace layout (aliased by lifetime; high-water 83,733,248 B)
    char* w = (char*)d_ws;
    int* flags      = (int*)(w + 0);              // 3 ints
    int* rowptr     = (int*)(w + 640);            // 100001 ints
    ushort* wbf     = (ushort*)(w + 400768);      // 65792 shorts
    int* csr        = (int*)(w + 532480);         // 1600064 ints (64 pad)
    float* gsum     = (float*)(w + 6933248);      // 256KB pooled sums
    uchar* mbuf     = (uchar*)(w + 32533248);     // 12.8MB fp8 mean (CSR-era aliases below)
    int* bucketBase = (int*)(w + 32533248);       //   257 ints  (dead after k_csr)
    int* blkcnt     = (int*)(w + 32534528);       //   256*256 [bucket][block] (dead after bscan_a)
    int* blkbase    = (int*)(w + 32796672);       //   256*256 [bucket][block] (dead after k_bin)
    int* tot        = (int*)(w + 33058816);       //   256 ints (dead after bscan_b)
    uchar* h1f8     = (uchar*)(w + 58133248);     // 12.8M fp8 h1
    int* binned     = (int*)(w + 58133248);       //   1.6M int packed (dead before gemm1)
    unsigned int* xf8 = (unsigned int*)(w + 70933248); // 12.8M fp8 x (as uints)

    dim3 blk256(256), blkNB(NB), blk128(128), blk512(512);

    k_prep<<<NB + 2048 + 257 + 256, blk256, 0, stream>>>(ei, x, batch, xf8,
                                                         W1l, W1r, W2l, W2r, b1, b2,
                                                         wbf, blkcnt, gsum, flags);
    k_bscan_a<<<NB, blkNB, 0, stream>>>(blkcnt, blkbase, tot);
    k_bscan_b<<<1, blkNB, 0, stream>>>(tot, bucketBase);
    k_bin<<<NB, blk256, 0, stream>>>(ei, blkbase, bucketBase, binned, flags);
    k_csr<<<NB, blk256, 0, stream>>>(binned, bucketBase, rowptr, csr);

    int agrid = N_NODES / 8 / 4;                 // 3125 (8 nodes/wave, 4 waves/block)

    // layer 1: agg over fp8 x -> mbuf(fp8); gemm (A0=mbuf, A1=xf8) -> h1f8 (fp8)
    k_agg<<<agrid, blk256, 0, stream>>>((const uint4*)xf8, rowptr, csr, (uint4*)mbuf);
    k_gemm<<<GGRID, blk512, 0, stream>>>(mbuf, (const uchar*)xf8,
                                         wbf + 0, wbf + 16384, wbf + 65536,
                                         h1f8, (float*)nullptr, nullptr, flags, 1);
    // layer 2: agg over fp8 h1 -> mbuf; gemm (A0=mbuf, A1=h1f8) -> fused pool into gsum
    k_agg<<<agrid, blk256, 0, stream>>>((const uint4*)h1f8, rowptr, csr, (uint4*)mbuf);
    k_gemm<<<GGRID, blk512, 0, stream>>>(mbuf, h1f8,
                                         wbf + 32768, wbf + 49152, wbf + 65664,
                                         (uchar*)nullptr, gsum, batch, flags, 0);
    // classify
    k_cls<<<N_GRAPHS, blk128, 0, stream>>>(gsum, batch, Wf, bf_, d_out, flags);
}

// Round 12
// 268.967 us; speedup vs baseline: 1.1125x; 1.1125x over previous
//
#include <hip/hip_runtime.h>
#include <hip/hip_bf16.h>

#define N_NODES 100000
#define N_EDGES 1600000
#define N_GRAPHS 512
#define NB 256                 // coarse dst-buckets
#define NPB 391                // nodes per bucket (256*391 = 100096 >= 100000)
#define CHUNK 6250             // edges per binning block (256*6250 = 1.6M exact)
#define STAGE 7680             // LDS csr staging per bucket (mean 6250, sd ~79)
#define GGROUPS 1563           // 64-row groups in gemm
#define GGRID 512              // gemm blocks (512 x 512thr = 1024 half-blocks, all resident)

typedef __attribute__((ext_vector_type(8))) short short8;
typedef __attribute__((ext_vector_type(4))) float f32x4;
typedef __attribute__((ext_vector_type(2))) float f32x2;

// ---- bf16 helpers ----
__device__ __forceinline__ float b2f(ushort u) {
    union { unsigned int i; float f; } c; c.i = ((unsigned int)u) << 16; return c.f;
}
__device__ __forceinline__ float blo(unsigned int u) {
    union { unsigned int i; float f; } c; c.i = u << 16; return c.f;
}
__device__ __forceinline__ float bhi(unsigned int u) {
    union { unsigned int i; float f; } c; c.i = u & 0xffff0000u; return c.f;
}
__device__ __forceinline__ ushort f2b(float f) {  // round-to-nearest-even
    union { float f; unsigned int i; } c; c.f = f;
    unsigned int r = (c.i + 0x7fffu + ((c.i >> 16) & 1u)) >> 16;
    return (ushort)r;
}
__device__ __forceinline__ unsigned int fbits(float f) {
    union { float f; unsigned int i; } c; c.f = f; return c.i;
}
__device__ __forceinline__ int idx_at(const void* p, long i, int f) {
    return f ? (int)((const long long*)p)[i] : ((const int*)p)[i];
}
// decode 8 packed fp8 -> short8 of bf16.
// fp8->f32 exact; bf16 mantissa (7b) superset of e4m3 (3b): truncation exact
// -> hi16 of two f32 packed with ONE v_perm_b32 each.
__device__ __forceinline__ short8 dec8(const uchar* p) {
    uint2 q = *(const uint2*)p;
    f32x2 d0 = __builtin_amdgcn_cvt_pk_f32_fp8((int)q.x, false);
    f32x2 d1 = __builtin_amdgcn_cvt_pk_f32_fp8((int)q.x, true);
    f32x2 d2 = __builtin_amdgcn_cvt_pk_f32_fp8((int)q.y, false);
    f32x2 d3 = __builtin_amdgcn_cvt_pk_f32_fp8((int)q.y, true);
    union { short8 s; unsigned int u[4]; } r;
    r.u[0] = __builtin_amdgcn_perm(fbits(d0.y), fbits(d0.x), 0x07060302u);
    r.u[1] = __builtin_amdgcn_perm(fbits(d1.y), fbits(d1.x), 0x07060302u);
    r.u[2] = __builtin_amdgcn_perm(fbits(d2.y), fbits(d2.x), 0x07060302u);
    r.u[3] = __builtin_amdgcn_perm(fbits(d3.y), fbits(d3.x), 0x07060302u);
    return r.s;
}

// ---- 1. fused prep (flags detected locally per block; block 0 publishes
//      global flags incl. batch dtype — no separate k_flags launch):
//      [0,NB) bucket-hist (TRANSPOSED store: blkcnt[bucket][block]) |
//      [NB,NB+2048) cvt x -> xf8 | [.., +257) cvt_w | last 256 blocks zero gsum
__global__ __launch_bounds__(256) void k_prep(const void* __restrict__ ei,
                                              const void* __restrict__ x,
                                              const void* __restrict__ batch,
                                              unsigned int* __restrict__ xf8,
                                              const void* W1l, const void* W1r,
                                              const void* W2l, const void* W2r,
                                              const void* b1,  const void* b2,
                                              ushort* __restrict__ wbf,
                                              int* __restrict__ blkcnt,
                                              float* __restrict__ gsum,
                                              int* __restrict__ flags) {
    int b = blockIdx.x, t = threadIdx.x;
    __shared__ int cf, ce, cb;
    int f0 = 0, f1 = 0;
    if (b < NB + 2048 + 257) {               // zero-gsum blocks skip detection
        if (t == 0) { cf = 0; ce = 0; cb = 0; }
        __syncthreads();
        unsigned int w = ((const unsigned int*)x)[t];
        unsigned int e = (w >> 7) & 0xffu;
        if (e >= 110u && e <= 130u) atomicAdd(&cf, 1);
        if (t < 128) {
            if (((const unsigned int*)ei)[2 * t + 1] != 0u) atomicAdd(&ce, 1);
            if (b == 0 && ((const int*)batch)[99001 + 2 * t] != 0) atomicAdd(&cb, 1);
        }
        __syncthreads();
        f0 = (cf >= 128) ? 1 : 0;
        f1 = (ce == 0) ? 1 : 0;
        if (b == 0 && t == 0) {
            flags[0] = f0;
            flags[1] = f1;
            flags[2] = (cb == 0) ? 1 : 0;
        }
    }
    if (b < NB) {
        __shared__ int h[NB];
        for (int j = t; j < NB; j += 256) h[j] = 0;
        __syncthreads();
        int lo = b * CHUNK, hi = lo + CHUNK;
        for (int e = lo + t; e < hi; e += 256) {
            int d = idx_at(ei, (long)N_EDGES + e, f1);
            atomicAdd(&h[d / NPB], 1);
        }
        __syncthreads();
        if (t < NB) blkcnt[t * NB + b] = h[t];   // transposed: [bucket][block]
    } else if (b < NB + 2048) {
        bool f32src = (f0 == 0);
        int vb = b - NB;
        const long nG = (long)N_NODES * 128 / 4;   // 3.2M groups of 4 feats
        for (long g = (long)vb * 256 + t; g < nG; g += 2048L * 256) {
            float v0, v1, v2, v3;
            if (f32src) {
                float4 vv = ((const float4*)x)[g];
                v0 = vv.x; v1 = vv.y; v2 = vv.z; v3 = vv.w;
            } else {
                uint2 q = ((const uint2*)x)[g];
                v0 = blo(q.x); v1 = bhi(q.x); v2 = blo(q.y); v3 = bhi(q.y);
            }
            int r = __builtin_amdgcn_cvt_pk_fp8_f32(v0, v1, 0, false);
            r = __builtin_amdgcn_cvt_pk_fp8_f32(v2, v3, r, true);
            xf8[g] = (unsigned int)r;
        }
    } else if (b < NB + 2048 + 257) {
        // weights+biases -> bf16: W1l@0 W1r@16384 W2l@32768 W2r@49152 b1@65536 b2@65664
        int idx = (b - NB - 2048) * 256 + t;
        if (idx >= 65792) return;
        const void* src; int off;
        if      (idx < 16384) { src = W1l; off = idx; }
        else if (idx < 32768) { src = W1r; off = idx - 16384; }
        else if (idx < 49152) { src = W2l; off = idx - 32768; }
        else if (idx < 65536) { src = W2r; off = idx - 49152; }
        else if (idx < 65664) { src = b1;  off = idx - 65536; }
        else                  { src = b2;  off = idx - 65664; }
        wbf[idx] = (f0 != 0) ? ((const ushort*)src)[off]
                             : f2b(((const float*)src)[off]);
    } else {
        int idx = (b - NB - 2048 - 257) * 256 + t;   // 256 blocks * 256 = 65536 exact
        gsum[idx] = 0.f;
    }
}

// ---- 2a. parallel per-bucket block-prefix: 256 blocks, block j = bucket j.
//      Coalesced load of blkcnt[j][0..255], LDS scan, write within-bucket
//      exclusive prefix to blkbase[j][blk] and bucket total to tot[j]. ----
__global__ __launch_bounds__(NB) void k_bscan_a(const int* __restrict__ blkcnt,
                                                int* __restrict__ blkbase,
                                                int* __restrict__ tot) {
    __shared__ int s[NB];
    int j = blockIdx.x, t = threadIdx.x;
    int v = blkcnt[j * NB + t];
    s[t] = v; __syncthreads();
    for (int off = 1; off < NB; off <<= 1) {
        int a = (t >= off) ? s[t - off] : 0;
        __syncthreads();
        s[t] += a;
        __syncthreads();
    }
    blkbase[j * NB + t] = s[t] - v;          // exclusive within bucket
    if (t == NB - 1) tot[j] = s[t];
}

// ---- 2b. tiny cross-bucket scan: bucketBase = exclusive prefix of tot ----
__global__ __launch_bounds__(NB) void k_bscan_b(const int* __restrict__ tot,
                                                int* __restrict__ bucketBase) {
    __shared__ int s[NB];
    int t = threadIdx.x;
    int v = tot[t];
    s[t] = v; __syncthreads();
    for (int off = 1; off < NB; off <<= 1) {
        int a = (t >= off) ? s[t - off] : 0;
        __syncthreads();
        s[t] += a;
        __syncthreads();
    }
    bucketBase[t] = s[t] - v;
    if (t == NB - 1) bucketBase[NB] = s[t];
}

// ---- 3. bin edges into buckets; packed entry = src | (loc<<20) ----
__global__ __launch_bounds__(256) void k_bin(const void* __restrict__ ei,
                                             const int* __restrict__ blkbase,
                                             const int* __restrict__ bucketBase,
                                             int* __restrict__ binned,
                                             const int* __restrict__ flags) {
    __shared__ int bb[NB];
    __shared__ int rank[NB];
    int t = threadIdx.x, blk = blockIdx.x;
    int f = flags[1];
    for (int j = t; j < NB; j += 256) {
        bb[j] = blkbase[j * NB + blk] + bucketBase[j];
        rank[j] = 0;
    }
    __syncthreads();
    int lo = blk * CHUNK, hi = lo + CHUNK;
    for (int e = lo + t; e < hi; e += 256) {
        int s = idx_at(ei, e, f);
        int d = idx_at(ei, (long)N_EDGES + e, f);
        int b = d / NPB;
        int loc = d - b * NPB;              // 0..390, fits in 9 bits
        int r = atomicAdd(&rank[b], 1);
        binned[bb[b] + r] = s | (loc << 20);
    }
}

// ---- 4. per-bucket CSR in LDS, coalesced flush ----
__global__ __launch_bounds__(256) void k_csr(const int* __restrict__ binned,
                                             const int* __restrict__ bucketBase,
                                             int* __restrict__ rowptr,
                                             int* __restrict__ csr) {
    __shared__ int cnt[400];
    __shared__ int sc[400];
    __shared__ int sh[256];
    __shared__ int stage[STAGE];  // 30 KB
    int t = threadIdx.x, b = blockIdx.x;
    int nodeLo = b * NPB;
    int nC = N_NODES - nodeLo; if (nC > NPB) nC = NPB;
    int eBase = bucketBase[b], eEnd = bucketBase[b + 1];

    for (int j = t; j < 400; j += 256) cnt[j] = 0;
    __syncthreads();
    for (int i = eBase + t; i < eEnd; i += 256)
        atomicAdd(&cnt[binned[i] >> 20], 1);
    __syncthreads();
    int base = t * 2;
    int v0 = (base < 400) ? cnt[base] : 0;
    int v1 = (base + 1 < 400) ? cnt[base + 1] : 0;
    int ssum = v0 + v1;
    sh[t] = ssum; __syncthreads();
    for (int off = 1; off < 256; off <<= 1) {
        int a = (t >= off) ? sh[t - off] : 0;
        __syncthreads();
        sh[t] += a;
        __syncthreads();
    }
    int pre = sh[t] - ssum;
    if (base < 400) sc[base] = pre;
    if (base + 1 < 400) sc[base + 1] = pre + v0;
    __syncthreads();
    for (int j = t; j < nC; j += 256) rowptr[nodeLo + j] = eBase + sc[j];
    if (b == NB - 1) {
        if (t == 0) rowptr[N_NODES] = eEnd;
        if (t < 64) csr[N_EDGES + t] = 0;   // pad (agg clamps anyway)
    }
    for (int j = t; j < 400; j += 256) cnt[j] = 0;  // reuse as rank
    __syncthreads();
    for (int i = eBase + t; i < eEnd; i += 256) {
        int p = binned[i];
        int loc = p >> 20;
        int pos = sc[loc] + atomicAdd(&cnt[loc], 1);
        int srcn = p & 0xFFFFF;
        if (pos < STAGE) stage[pos] = srcn;
        else csr[eBase + pos] = srcn;   // statistical never
    }
    __syncthreads();
    int eCnt = eEnd - eBase; if (eCnt > STAGE) eCnt = STAGE;
    for (int j = t; j < eCnt; j += 256) csr[eBase + j] = stage[j];
}

// ---- 5. mean aggregation over fp8 rows: 8 nodes per wave (8 lanes each).
//      r7/r10 config: NO occupancy pin (r11's (256,6) forced VGPR 40 -> spill,
//      +32MB scratch writes, +22us). Natural VGPR ~72, 8-deep gather loop.
//      At this config agg is at its cache-BW floor (~3.4 TB/s L2-miss gather).
__global__ __launch_bounds__(256) void k_agg(const uint4* __restrict__ x8,
                                             const int* __restrict__ rowptr,
                                             const int* __restrict__ csr,
                                             uint4* __restrict__ mout) {
    int wv = blockIdx.x * 4 + (threadIdx.x >> 6);   // wave id; 8 nodes per wave
    int lane = threadIdx.x & 63;
    int li = lane & 7;                              // lane within node-octet
    int node = wv * 8 + (lane >> 3);                // 100000 % 8 == 0: no tail
    int beg = rowptr[node];
    int end = rowptr[node + 1];
    int deg = end - beg;
    f32x2 a2[8] = {};
    int full = deg & ~7;
    int j = 0;
    for (; j < full; j += 8) {                      // all 8 edges valid: no guards
        int vidx = csr[beg + j + li];
        uint4 p[8];
#pragma unroll
        for (int i = 0; i < 8; ++i) {
            int idx = __shfl(vidx, i | (lane & 56));  // stays within 8-lane group
            p[i] = x8[(long)idx * 8 + li];            // 16 fp8 feats per lane
        }
#pragma unroll
        for (int i = 0; i < 8; ++i) {
            a2[0] += __builtin_amdgcn_cvt_pk_f32_fp8((int)p[i].x, false);
            a2[1] += __builtin_amdgcn_cvt_pk_f32_fp8((int)p[i].x, true);
            a2[2] += __builtin_amdgcn_cvt_pk_f32_fp8((int)p[i].y, false);
            a2[3] += __builtin_amdgcn_cvt_pk_f32_fp8((int)p[i].y, true);
            a2[4] += __builtin_amdgcn_cvt_pk_f32_fp8((int)p[i].z, false);
            a2[5] += __builtin_amdgcn_cvt_pk_f32_fp8((int)p[i].z, true);
            a2[6] += __builtin_amdgcn_cvt_pk_f32_fp8((int)p[i].w, false);
            a2[7] += __builtin_amdgcn_cvt_pk_f32_fp8((int)p[i].w, true);
        }
    }
    if (j < deg) {                                  // <=7 remaining, group-uniform
        int pos = beg + j + li;
        if (pos > end - 1) pos = end - 1;           // deg>0 here, so valid
        int vidx = csr[pos];
#pragma unroll
        for (int i = 0; i < 8; ++i) {
            int idx = __shfl(vidx, i | (lane & 56));
            uint4 p = x8[(long)idx * 8 + li];       // dup loads hit L1
            bool ok = (j + i < deg);
            unsigned int q0 = ok ? p.x : 0u;        // fp8 0x00 == 0.0
            unsigned int q1 = ok ? p.y : 0u;
            unsigned int q2 = ok ? p.z : 0u;
            unsigned int q3 = ok ? p.w : 0u;
            a2[0] += __builtin_amdgcn_cvt_pk_f32_fp8((int)q0, false);
            a2[1] += __builtin_amdgcn_cvt_pk_f32_fp8((int)q0, true);
            a2[2] += __builtin_amdgcn_cvt_pk_f32_fp8((int)q1, false);
            a2[3] += __builtin_amdgcn_cvt_pk_f32_fp8((int)q1, true);
            a2[4] += __builtin_amdgcn_cvt_pk_f32_fp8((int)q2, false);
            a2[5] += __builtin_amdgcn_cvt_pk_f32_fp8((int)q2, true);
            a2[6] += __builtin_amdgcn_cvt_pk_f32_fp8((int)q3, false);
            a2[7] += __builtin_amdgcn_cvt_pk_f32_fp8((int)q3, true);
        }
    }
    float s = (deg > 0) ? 1.f / (float)deg : 0.f;
    uint4 o;
    int r;
    r = __builtin_amdgcn_cvt_pk_fp8_f32(a2[0].x * s, a2[0].y * s, 0, false);
    r = __builtin_amdgcn_cvt_pk_fp8_f32(a2[1].x * s, a2[1].y * s, r, true);  o.x = (unsigned int)r;
    r = __builtin_amdgcn_cvt_pk_fp8_f32(a2[2].x * s, a2[2].y * s, 0, false);
    r = __builtin_amdgcn_cvt_pk_fp8_f32(a2[3].x * s, a2[3].y * s, r, true);  o.y = (unsigned int)r;
    r = __builtin_amdgcn_cvt_pk_fp8_f32(a2[4].x * s, a2[4].y * s, 0, false);
    r = __builtin_amdgcn_cvt_pk_fp8_f32(a2[5].x * s, a2[5].y * s, r, true);  o.z = (unsigned int)r;
    r = __builtin_amdgcn_cvt_pk_fp8_f32(a2[6].x * s, a2[6].y * s, 0, false);
    r = __builtin_amdgcn_cvt_pk_fp8_f32(a2[7].x * s, a2[7].y * s, r, true);  o.w = (unsigned int)r;
    mout[(long)node * 8 + li] = o;
}

// ---- 6. persistent fused SAGE linear: out = relu([A0|A1] @ [Wl;Wr]^T + b) ----
// FROZEN r9 config: 512-thread blocks (two independent halves, one 64KB Ws),
// 16 waves/CU, VGPR<=128 (no spill), serialized tiles, balanced partition.
__global__ __launch_bounds__(512, 2) void k_gemm(const uchar* __restrict__ A0f8,
                                                 const uchar* __restrict__ A1f8,
                                                 const ushort* __restrict__ Wl,
                                                 const ushort* __restrict__ Wr,
                                                 const ushort* __restrict__ bias,
                                                 uchar* __restrict__ out8,
                                                 float* __restrict__ gsum,
                                                 const void* __restrict__ batch,
                                                 const int* __restrict__ flags,
                                                 int layer1) {
    __shared__ short Ws[4096 * 8];  // 64 KiB fragment-interleaved weights (shared by both halves)
    int t = threadIdx.x;
#pragma unroll
    for (int i = 0; i < 8; ++i) {
        int f = i * 512 + t;
        int ln = f & 63, kk = (f >> 6) & 7, tile = f >> 9;
        int o = tile * 16 + (ln & 15);
        int k0 = kk * 32 + ((ln >> 4) * 8);
        const ushort* wsrc = (k0 < 128) ? (Wl + o * 128 + k0)
                                        : (Wr + o * 128 + (k0 - 128));
        *(short8*)&Ws[f * 8] = *(const short8*)wsrc;
    }
    __syncthreads();

    int half = t >> 8;              // which 256-thread half-block
    int tt = t & 255;
    int wid = tt >> 6, lane = tt & 63;
    int kq = (lane >> 4) * 8;
    int bflag = layer1 ? 0 : flags[2];

    // hoist bias for this lane's output column across all 8 tiles (8 VGPR)
    float bo8[8];
#pragma unroll
    for (int tile = 0; tile < 8; ++tile)
        bo8[tile] = b2f(bias[tile * 16 + (lane & 15)]);

    int h = blockIdx.x * 2 + half;               // 0..1023
    int gbeg = (h * GGROUPS) >> 10;              // balanced contiguous partition
    int gend = ((h + 1) * GGROUPS) >> 10;

    for (int g = gbeg; g < gend; ++g) {
        long nbase = (long)g * 64 + (long)wid * 16;
        int arow = (int)nbase + (lane & 15);
        if (arow >= N_NODES) arow = N_NODES - 1;   // clamp (stores guarded)

        short8 afrag[8];
#pragma unroll
        for (int kk = 0; kk < 8; ++kk) {
            int k0 = kk * 32 + kq;
            afrag[kk] = (k0 < 128)
                ? dec8(A0f8 + (long)arow * 128 + k0)
                : dec8(A1f8 + (long)arow * 128 + (k0 - 128));
        }

        int bg[4]; int guni = 0; bool uniform = false;
        if (!layer1) {
            int bmin = 0x7fffffff, bmax = -0x7fffffff;
#pragma unroll
            for (int r = 0; r < 4; ++r) {
                long node = nbase + (lane >> 4) * 4 + r;
                if (node < N_NODES) {
                    int bb = idx_at(batch, node, bflag);
                    bg[r] = bb;
                    bmin = min(bmin, bb); bmax = max(bmax, bb);
                } else { bg[r] = 0; bmax = 0x7fffffff; }  // force slow path on tail
            }
            bmin = min(bmin, __shfl_xor(bmin, 16));
            bmin = min(bmin, __shfl_xor(bmin, 32));
            bmax = max(bmax, __shfl_xor(bmax, 16));
            bmax = max(bmax, __shfl_xor(bmax, 32));
            uniform = (bmin == bmax);
            guni = bmin;
        }

#pragma unroll 1
        for (int tile = 0; tile < 8; ++tile) {
            f32x4 acc = {0.f, 0.f, 0.f, 0.f};
#pragma unroll
            for (int kk = 0; kk < 8; ++kk) {
                short8 bfrag = *(short8*)&Ws[((tile * 8 + kk) * 64 + lane) * 8];
                acc = __builtin_amdgcn_mfma_f32_16x16x32_bf16(afrag[kk], bfrag, acc, 0, 0, 0);
            }
            int o = tile * 16 + (lane & 15);
            float bo = bo8[tile];
            if (layer1) {
#pragma unroll
                for (int r = 0; r < 4; ++r) {
                    long node = nbase + (lane >> 4) * 4 + r;
                    if (node < N_NODES) {
                        float v = acc[r] + bo;
                        v = v > 0.f ? v : 0.f;
                        int pp = __builtin_amdgcn_cvt_pk_fp8_f32(v, v, 0, false);
                        out8[node * 128 + o] = (uchar)pp;
                    }
                }
            } else if (uniform) {
                float s = 0.f;
#pragma unroll
                for (int r = 0; r < 4; ++r) {
                    float v = acc[r] + bo;
                    s += (v > 0.f ? v : 0.f);
                }
                s += __shfl_xor(s, 16);
                s += __shfl_xor(s, 32);
                if ((lane >> 4) == 0) atomicAdd(&gsum[guni * 128 + o], s);
            } else {
#pragma unroll
                for (int r = 0; r < 4; ++r) {
                    long node = nbase + (lane >> 4) * 4 + r;
                    if (node < N_NODES) {
                        float v = acc[r] + bo;
                        v = v > 0.f ? v : 0.f;
                        atomicAdd(&gsum[bg[r] * 128 + o], v);
                    }
                }
            }
        }
    }
}

// ---- 7. tiny classifier: mean = gsum/cnt ; logits = Wf@mean + bf ; log_softmax ----
__global__ __launch_bounds__(128) void k_cls(const float* __restrict__ gsum,
                                             const void* __restrict__ batch,
                                             const void* __restrict__ Wf,
                                             const void* __restrict__ bfv,
                                             void* __restrict__ outp,
                                             const int* __restrict__ flags) {
    int g = blockIdx.x, t = threadIdx.x;
    bool f32 = (flags[0] == 0);
    int b64 = flags[2];
    __shared__ int rng[2];
    __shared__ float gv[128];
    __shared__ float lg[10];
    if (t < 2) {
        int v = g + t, lo = 0, hi = N_NODES;
        while (lo < hi) {
            int mid = (lo + hi) >> 1;
            if (idx_at(batch, mid, b64) < v) lo = mid + 1; else hi = mid;
        }
        rng[t] = lo;
    }
    __syncthreads();
    int cnt = rng[1] - rng[0];
    float c = (cnt > 0) ? (float)cnt : 1.f;
    gv[t] = gsum[g * 128 + t] / c;
    __syncthreads();
    if (t < 10) {
        float s = f32 ? ((const float*)bfv)[t] : b2f(((const ushort*)bfv)[t]);
        for (int k = 0; k < 128; ++k) {
            float wv = f32 ? ((const float*)Wf)[t * 128 + k] : b2f(((const ushort*)Wf)[t * 128 + k]);
            s += gv[k] * wv;
        }
        lg[t] = s;
    }
    __syncthreads();
    if (t == 0) {
        float mx = lg[0];
        for (int i = 1; i < 10; ++i) mx = fmaxf(mx, lg[i]);
        float se = 0.f;
        for (int i = 0; i < 10; ++i) se += expf(lg[i] - mx);
        float lse = mx + logf(se);
        for (int i = 0; i < 10; ++i) {
            float v = lg[i] - lse;
            if (f32) ((float*)outp)[g * 10 + i] = v;
            else     ((ushort*)outp)[g * 10 + i] = f2b(v);
        }
    }
}

extern "C" void kernel_launch(void* const* d_in, const int* in_sizes, int n_in,
                              void* d_out, int out_size, void* d_ws, size_t ws_size,
                              hipStream_t stream) {
    const void* x     = d_in[0];
    const void* ei    = d_in[1];
    const void* batch = d_in[2];
    const void* W1l = d_in[3];
    const void* b1  = d_in[4];
    const void* W1r = d_in[5];
    const void* W2l = d_in[6];
    const void* b2  = d_in[7];
    const void* W2r = d_in[8];
    const void* Wf  = d_in[9];
    const void* bf_ = d_in[10];

    // workspace layout (aliased by lifetime; high-water 83,733,248 B)
    char* w = (char*)d_ws;
    int* flags      = (int*)(w + 0);              // 3 ints
    int* rowptr     = (int*)(w + 640);            // 100001 ints
    ushort* wbf     = (ushort*)(w + 400768);      // 65792 shorts
    int* csr        = (int*)(w + 532480);         // 1600064 ints (64 pad)
    float* gsum     = (float*)(w + 6933248);      // 256KB pooled sums
    uchar* mbuf     = (uchar*)(w + 32533248);     // 12.8MB fp8 mean (CSR-era aliases below)
    int* bucketBase = (int*)(w + 32533248);       //   257 ints  (dead after k_csr)
    int* blkcnt     = (int*)(w + 32534528);       //   256*256 [bucket][block] (dead after bscan_a)
    int* blkbase    = (int*)(w + 32796672);       //   256*256 [bucket][block] (dead after k_bin)
    int* tot        = (int*)(w + 33058816);       //   256 ints (dead after bscan_b)
    uchar* h1f8     = (uchar*)(w + 58133248);     // 12.8M fp8 h1
    int* binned     = (int*)(w + 58133248);       //   1.6M int packed (dead before gemm1)
    unsigned int* xf8 = (unsigned int*)(w + 70933248); // 12.8M fp8 x (as uints)

    dim3 blk256(256), blkNB(NB), blk128(128), blk512(512);

    k_prep<<<NB + 2048 + 257 + 256, blk256, 0, stream>>>(ei, x, batch, xf8,
                                                         W1l, W1r, W2l, W2r, b1, b2,
                                                         wbf, blkcnt, gsum, flags);
    k_bscan_a<<<NB, blkNB, 0, stream>>>(blkcnt, blkbase, tot);
    k_bscan_b<<<1, blkNB, 0, stream>>>(tot, bucketBase);
    k_bin<<<NB, blk256, 0, stream>>>(ei, blkbase, bucketBase, binned, flags);
    k_csr<<<NB, blk256, 0, stream>>>(binned, bucketBase, rowptr, csr);

    int agrid = N_NODES / 8 / 4;                 // 3125 (8 nodes/wave, 4 waves/block)

    // layer 1: agg over fp8 x -> mbuf(fp8); gemm (A0=mbuf, A1=xf8) -> h1f8 (fp8)
    k_agg<<<agrid, blk256, 0, stream>>>((const uint4*)xf8, rowptr, csr, (uint4*)mbuf);
    k_gemm<<<GGRID, blk512, 0, stream>>>(mbuf, (const uchar*)xf8,
                                         wbf + 0, wbf + 16384, wbf + 65536,
                                         h1f8, (float*)nullptr, nullptr, flags, 1);
    // layer 2: agg over fp8 h1 -> mbuf; gemm (A0=mbuf, A1=h1f8) -> fused pool into gsum
    k_agg<<<agrid, blk256, 0, stream>>>((const uint4*)h1f8, rowptr, csr, (uint4*)mbuf);
    k_gemm<<<GGRID, blk512, 0, stream>>>(mbuf, h1f8,
                                         wbf + 32768, wbf + 49152, wbf + 65664,
                                         (uchar*)nullptr, gsum, batch, flags, 0);
    // classify
    k_cls<<<N_GRAPHS, blk128, 0, stream>>>(gsum, batch, Wf, bf_, d_out, flags);
}